// Round 14
// baseline (5030.957 us; speedup 1.0000x reference)
//
#include <hip/hip_runtime.h>

// Problem constants
#define T_ 512
#define B_ 256
#define I_ 128
#define H_ 256
#define SPIN_MAX (1 << 18)

typedef unsigned short ushort_t;
typedef unsigned int uint_t;
typedef unsigned long long u64_t;
typedef __attribute__((ext_vector_type(8))) short short8;  // 8 bf16 (4 VGPRs)
typedef __attribute__((ext_vector_type(4))) float f32x4;

// ---- workspace layout (u32 units) ----
// xg  [16 g][4 slot][16 row][768] f32 : L0 x-part gate partials (r|z|n segments)
// h0r [16][4][16][256] u32           : h0 packed hi|mid bf16 planes
// qa  [16][4][16][512] f32           : L1 Q-side partials (r|z)
// qb  [16][4][16][256] f32           : L1 n1 partials
#define XG_OFF   0
#define H0R_OFF  786432
#define QA_OFF   1048576
#define QB_OFF   1572864
#define FL_OFF   1835008
#define N_FLAGS  2048
// flags per group (stride 32): [0..7]=sX[wv] [8]=sH0 [9]=sR [10..17]=sQa[wv] [18..25]=sQb[wv]
//        [1024+bid]=xcd  [1536+g*16]=arrival counter (target 5)

__device__ __forceinline__ ushort_t f2bf(float f) {  // RNE f32->bf16
  unsigned int u = __float_as_uint(f);
  u += 0x7fffu + ((u >> 16) & 1u);
  return (ushort_t)(u >> 16);
}
__device__ __forceinline__ float bf2f(ushort_t u) {
  return __uint_as_float(((unsigned int)u) << 16);
}

// ---------------- prep: flag zeroing only ----------------
__global__ void prep_kernel(uint_t* __restrict__ ws) {
  int i = blockIdx.x * 256 + threadIdx.x;
  if (i < N_FLAGS) ((int*)(ws + FL_OFF))[i] = 0;
}

// ---------------- fragment helpers (verified gfx950 16x16x32 layouts) ----------------
struct frag2 { short8 h, m; };

// x A-frag: split fp32 into 2 bf16 planes
__device__ __forceinline__ frag2 lda_x2(const float* base, int ldk, int kc, int lane) {
  const float* p = base + (size_t)(lane & 15) * ldk + kc * 32 + ((lane >> 4) << 3);
  f32x4 a = *(const f32x4*)p;
  f32x4 b = *(const f32x4*)(p + 4);
  float v[8] = {a[0], a[1], a[2], a[3], b[0], b[1], b[2], b[3]};
  frag2 r;
#pragma unroll
  for (int j = 0; j < 8; j++) {
    float f = v[j];
    ushort_t xx = f2bf(f); f -= bf2f(xx);
    ushort_t y = f2bf(f);
    r.h[j] = (short)xx; r.m[j] = (short)y;
  }
  return r;
}
// 1-plane weight B-frag (R7-validated numerics)
__device__ __forceinline__ short8 ldw1(const float* base, int ldk, int row, int kc, int lane) {
  const float* p = base + (size_t)(row + (lane & 15)) * ldk + kc * 32 + ((lane >> 4) << 3);
  f32x4 a = *(const f32x4*)p;
  f32x4 b = *(const f32x4*)(p + 4);
  short8 r;
  r[0] = (short)f2bf(a[0]); r[1] = (short)f2bf(a[1]);
  r[2] = (short)f2bf(a[2]); r[3] = (short)f2bf(a[3]);
  r[4] = (short)f2bf(b[0]); r[5] = (short)f2bf(b[1]);
  r[6] = (short)f2bf(b[2]); r[7] = (short)f2bf(b[3]);
  return r;
}
// packed-h A-frag from L2 ring: 4x8B tracked agent-relaxed loads + decode
__device__ __forceinline__ frag2 ld_packed(const uint_t* p) {
  const u64_t* qp = (const u64_t*)p;
  u64_t d0 = __hip_atomic_load(qp + 0, __ATOMIC_RELAXED, __HIP_MEMORY_SCOPE_AGENT);
  u64_t d1 = __hip_atomic_load(qp + 1, __ATOMIC_RELAXED, __HIP_MEMORY_SCOPE_AGENT);
  u64_t d2 = __hip_atomic_load(qp + 2, __ATOMIC_RELAXED, __HIP_MEMORY_SCOPE_AGENT);
  u64_t d3 = __hip_atomic_load(qp + 3, __ATOMIC_RELAXED, __HIP_MEMORY_SCOPE_AGENT);
  u64_t d[4] = {d0, d1, d2, d3};
  frag2 f;
#pragma unroll
  for (int j = 0; j < 4; j++) {
    uint_t lo = (uint_t)d[j];
    uint_t hi = (uint_t)(d[j] >> 32);
    f.h[2 * j]     = (short)(lo & 0xffffu); f.m[2 * j]     = (short)(lo >> 16);
    f.h[2 * j + 1] = (short)(hi & 0xffffu); f.m[2 * j + 1] = (short)(hi >> 16);
  }
  return f;
}
// f32 load via agent-relaxed atomic (L1-bypass, compiler-tracked)
__device__ __forceinline__ float ldf32(const uint_t* p) {
  uint_t v = __hip_atomic_load(p, __ATOMIC_RELAXED, __HIP_MEMORY_SCOPE_AGENT);
  return __uint_as_float(v);
}
#define CFENCE() asm volatile("" ::: "memory")

__device__ __forceinline__ f32x4 mfma_(short8 a, short8 b, f32x4 c) {
  return __builtin_amdgcn_mfma_f32_16x16x32_bf16(a, b, c, 0, 0, 0);
}
// per-lane-mapped poll: lane spins (act && tgt>0) until *p >= tgt; wave exits on __all
__device__ __forceinline__ int lpoll(const int* p, int tgt, int act, int aborted) {
  if (aborted) return aborted;
  int n = 0;
  for (;;) {
    int ok = 1;
    if (act && tgt > 0)
      ok = (__hip_atomic_load(p, __ATOMIC_RELAXED, __HIP_MEMORY_SCOPE_AGENT) >= tgt);
    if (__all(ok)) return 0;
    if (++n > SPIN_MAX) return 1;
  }
}
// single-shot check (prefetch of next step's condition, off the critical path)
__device__ __forceinline__ int lcheck(const int* p, int tgt, int act) {
  int ok = 1;
  if (act && tgt > 0)
    ok = (__hip_atomic_load(p, __ATOMIC_RELAXED, __HIP_MEMORY_SCOPE_AGENT) >= tgt);
  return __all(ok);
}
__device__ __forceinline__ void stflag(int* p, int v) {
  __hip_atomic_store(p, v, __ATOMIC_RELAXED, __HIP_MEMORY_SCOPE_AGENT);
}
__device__ __forceinline__ int get_xcc() {
  int x;
  asm volatile("s_getreg_b32 %0, hwreg(HW_REG_XCC_ID)" : "=s"(x));
  return x & 15;
}
// GRU pointwise, fast transcendentals (R7-validated)
__device__ __forceinline__ float cellpw_fast(float gr, float gz, float np, float h) {
  float r = __builtin_amdgcn_rcpf(1.0f + __builtin_amdgcn_exp2f(-1.44269504089f * gr));
  float z = __builtin_amdgcn_rcpf(1.0f + __builtin_amdgcn_exp2f(-1.44269504089f * gz));
  float a = np + r * h;
  float n = 1.0f - 2.0f * __builtin_amdgcn_rcpf(1.0f + __builtin_amdgcn_exp2f(2.88539008177f * a));
  return (1.0f - z) * n + z * h;
}

// -------- persistent kernel: 80 WGs x 512 thr (8 waves = 2/SIMD per CU) -------------
// Same 5-role dependency-split pipeline as R12 (1.7x win), but each role's columns are
// split across 8 waves instead of 4: per-wave weights halve (<=128 VGPR, fits 2
// waves/SIMD), per-wave MFMA halves, and the second wave per SIMD hides the other's
// MFMA-dependency and L2-load stalls (Guideline 1 applied INSIDE each stage).
// role = bid>>4: 0=X, 1=H0 (h0 recurrence INTRA-CU), 2=Qa, 3=Qb, 4=R (h1 INTRA-CU)
__global__ void __launch_bounds__(512, 2)
gru_main(const float* __restrict__ x,
         const float* __restrict__ Wi0, const float* __restrict__ Wh0, const float* __restrict__ Wn0,
         const float* __restrict__ Wi1, const float* __restrict__ Wh1, const float* __restrict__ Wn1,
         const float* __restrict__ state, float* __restrict__ out,
         uint_t* __restrict__ ws, int* __restrict__ unused_flags) {
  __shared__ ushort_t hp[2][2][16][264];  // [parity][plane][row][col] packed h planes
  __shared__ float hf[16][264];           // fp32 h carry
  __shared__ int s_fast;

  const int tid = (int)threadIdx.x;
  const int lane = tid & 63;
  const int wv = tid >> 6;                // wave 0..7
  const int bid = (int)blockIdx.x;
  const int g = bid & 15;
  const int role = bid >> 4;
  const int gb = g * 16;
  const int c0 = wv * 32;                 // this wave's 32 output cols (2 tiles)
  const int arow = lane & 15;
  const int acol = (lane >> 4) << 3;
  const int q = lane >> 4;

  int* flags = (int*)(ws + FL_OFF);
  int* fg = flags + g * 32;
  uint_t* xgp = ws + XG_OFF + (size_t)g * 49152;
  uint_t* h0r = ws + H0R_OFF + (size_t)g * 16384;
  uint_t* qap = ws + QA_OFF + (size_t)g * 32768;
  uint_t* qbp = ws + QB_OFF + (size_t)g * 16384;

  // ---- one-time group XCD-locality check (5 blocks) ----
  if (tid == 0) {
    int myx = get_xcc();
    __hip_atomic_store(&flags[1024 + bid], myx, __ATOMIC_RELAXED, __HIP_MEMORY_SCOPE_AGENT);
    __threadfence();
    __hip_atomic_fetch_add(&flags[1536 + g * 16], 1, __ATOMIC_RELEASE, __HIP_MEMORY_SCOPE_AGENT);
    int n = 0, ab = 0;
    while (__hip_atomic_load(&flags[1536 + g * 16], __ATOMIC_RELAXED,
                             __HIP_MEMORY_SCOPE_AGENT) < 5) {
      if (++n > SPIN_MAX) { ab = 1; break; }
    }
    __threadfence();
    int f = ab ? 0 : 1;
    if (!ab) {
#pragma unroll
      for (int r = 0; r < 5; r++)
        f &= (__hip_atomic_load(&flags[1024 + r * 16 + g], __ATOMIC_RELAXED,
                                __HIP_MEMORY_SCOPE_AGENT) == myx);
    }
    s_fast = f;
  }

  // ---- recurrence CUs: init h[-1] into LDS (parity 1) ----
  if (role == 1 || role == 4) {
    const float* st = state + (role == 4 ? (size_t)B_ * H_ : 0);
#pragma unroll
    for (int j = 0; j < 2; j++)
#pragma unroll
      for (int e = 0; e < 4; e++) {
        int row = q * 4 + e, col = c0 + 16 * j + (lane & 15);
        float f = st[(size_t)(gb + row) * H_ + col];
        hf[row][col] = f;
        ushort_t hi = f2bf(f), mid = f2bf(f - bf2f(hi));
        hp[1][0][row][col] = hi;
        hp[1][1][row][col] = mid;
      }
  }
  __syncthreads();
  const int fast = s_fast;
  int aborted = 0, ready = 0;
  const f32x4 zz = {0.f, 0.f, 0.f, 0.f};

  if (role == 0) {
    //=========== X: xg[t] = x[t] @ {Wi0 r,z ; Wn0} -- no recurrence, runs ahead ========
    short8 Wxr[2][4], Wxz[2][4], Wxn[2][4];  // 24 short8 = 96 VGPR
#pragma unroll
    for (int j = 0; j < 2; j++)
#pragma unroll
      for (int kc = 0; kc < 4; kc++) {
        Wxr[j][kc] = ldw1(Wi0, I_, c0 + 16 * j, kc, lane);
        Wxz[j][kc] = ldw1(Wi0, I_, 256 + c0 + 16 * j, kc, lane);
        Wxn[j][kc] = ldw1(Wn0, I_, c0 + 16 * j, kc, lane);
      }
    const int* wp = fg + 8;  // sH0 (WAR: ring depth 4)
    for (int t = 0; t < T_; t++) {
      if (!ready) aborted = lpoll(wp, t - 3, lane == 0, aborted);
      CFENCE();
      f32x4 ar[2] = {zz, zz}, az[2] = {zz, zz}, an[2] = {zz, zz};
      const float* xt = x + ((size_t)t * B_ + gb) * I_;
#pragma unroll
      for (int kc = 0; kc < 4; kc++) {
        frag2 a = lda_x2(xt, I_, kc, lane);
#pragma unroll
        for (int j = 0; j < 2; j++) {
          ar[j] = mfma_(a.h, Wxr[j][kc], ar[j]); ar[j] = mfma_(a.m, Wxr[j][kc], ar[j]);
          az[j] = mfma_(a.h, Wxz[j][kc], az[j]); az[j] = mfma_(a.m, Wxz[j][kc], az[j]);
          an[j] = mfma_(a.h, Wxn[j][kc], an[j]); an[j] = mfma_(a.m, Wxn[j][kc], an[j]);
        }
      }
      float* xs = (float*)(xgp + (size_t)(t & 3) * 12288);
#pragma unroll
      for (int j = 0; j < 2; j++)
#pragma unroll
        for (int e = 0; e < 4; e++) {
          int row = q * 4 + e, col = c0 + 16 * j + (lane & 15);
          xs[row * 768 + col] = ar[j][e];
          xs[row * 768 + 256 + col] = az[j][e];
          xs[row * 768 + 512 + col] = an[j][e];
        }
      asm volatile("s_waitcnt vmcnt(0)" ::: "memory");
      if (!fast) __threadfence();
      if (lane == 0) stflag(fg + wv, t + 1);
      ready = fast ? lcheck(wp, t - 2, lane == 0) : 0;
    }
  } else if (role == 1) {
    //=========== H0: h0 recurrence, INTRA-CU (LDS + one barrier per step) =============
    short8 Whr[2][8], Whz[2][8];  // 32 short8 = 128 VGPR
#pragma unroll
    for (int j = 0; j < 2; j++)
#pragma unroll
      for (int kc = 0; kc < 8; kc++) {
        Whr[j][kc] = ldw1(Wh0, H_, c0 + 16 * j, kc, lane);
        Whz[j][kc] = ldw1(Wh0, H_, 256 + c0 + 16 * j, kc, lane);
      }
    // lanes 0-7: sX[l]>=t+1 ; 8-15: sQa[l-8] WAR>=t-3 ; 16-23: sQb[l-16] WAR>=t-3
    const int hact = lane < 24;
    const int* hpn = fg + ((lane < 8) ? lane : (lane < 16 ? 10 + (lane - 8) : 18 + (lane - 16)));
    for (int t = 0; t < T_; t++) {
      if (!ready) aborted = lpoll(hpn, (lane < 8) ? t + 1 : t - 3, hact, aborted);
      if (!fast) __threadfence();
      CFENCE();
      const uint_t* xs = xgp + (size_t)(t & 3) * 12288;
      float xr[2][4], xz[2][4], xn[2][4];
#pragma unroll
      for (int j = 0; j < 2; j++)
#pragma unroll
        for (int e = 0; e < 4; e++) {
          int row = q * 4 + e, col = c0 + 16 * j + (lane & 15);
          xr[j][e] = ldf32(xs + row * 768 + col);
          xz[j][e] = ldf32(xs + row * 768 + 256 + col);
          xn[j][e] = ldf32(xs + row * 768 + 512 + col);
        }
      const int par = (t + 1) & 1;
      f32x4 accr[2] = {zz, zz}, accz[2] = {zz, zz};
#pragma unroll
      for (int kc = 0; kc < 8; kc++) {
        short8 ah = *(const short8*)&hp[par][0][arow][kc * 32 + acol];
        short8 am = *(const short8*)&hp[par][1][arow][kc * 32 + acol];
#pragma unroll
        for (int j = 0; j < 2; j++) {
          accr[j] = mfma_(ah, Whr[j][kc], accr[j]); accr[j] = mfma_(am, Whr[j][kc], accr[j]);
          accz[j] = mfma_(ah, Whz[j][kc], accz[j]); accz[j] = mfma_(am, Whz[j][kc], accz[j]);
        }
      }
      uint_t* hdst = h0r + (size_t)(t & 3) * 4096;
#pragma unroll
      for (int j = 0; j < 2; j++)
#pragma unroll
        for (int e = 0; e < 4; e++) {
          int row = q * 4 + e, col = c0 + 16 * j + (lane & 15);
          float gr = accr[j][e] + xr[j][e];
          float gz = accz[j][e] + xz[j][e];
          float h = hf[row][col];
          float hn = cellpw_fast(gr, gz, xn[j][e], h);
          hf[row][col] = hn;
          ushort_t hi = f2bf(hn), mid = f2bf(hn - bf2f(hi));
          hp[t & 1][0][row][col] = hi;
          hp[t & 1][1][row][col] = mid;
          hdst[row * 256 + col] = (uint_t)hi | ((uint_t)mid << 16);
        }
      __syncthreads();  // drains publishes (vmcnt) + orders LDS for next step
      if (tid == 0) { if (!fast) __threadfence(); stflag(fg + 8, t + 1); }
      ready = fast ? lcheck(hpn, (lane < 8) ? t + 2 : t - 2, hact) : 0;
    }
#pragma unroll
    for (int j = 0; j < 2; j++)
#pragma unroll
      for (int e = 0; e < 4; e++) {
        int row = q * 4 + e, col = c0 + 16 * j + (lane & 15);
        out[(size_t)T_ * B_ * H_ + (size_t)(gb + row) * H_ + col] = hf[row][col];
      }
  } else if (role == 2) {
    //=========== Qa: L1 r,z Q-side partials from h0[t] -- pipelined ===================
    short8 Wq[4][8];  // 2 r-tiles + 2 z-tiles = 32 short8 = 128 VGPR
#pragma unroll
    for (int kc = 0; kc < 8; kc++)
#pragma unroll
      for (int j = 0; j < 2; j++) {
        Wq[j][kc] = ldw1(Wi1, H_, c0 + 16 * j, kc, lane);
        Wq[2 + j][kc] = ldw1(Wi1, H_, 256 + c0 + 16 * j, kc, lane);
      }
    const int qact = lane < 2;  // lane0: sH0 >= t+1 ; lane1: sR WAR >= t-3
    const int* qpn = fg + ((lane == 0) ? 8 : 9);
    int* myslot = fg + 10 + wv;
    for (int t = 0; t < T_; t++) {
      if (!ready) aborted = lpoll(qpn, (lane == 0) ? t + 1 : t - 3, qact, aborted);
      if (!fast) __threadfence();
      CFENCE();
      frag2 A[8];
      const uint_t* src = h0r + (size_t)(t & 3) * 4096 + (size_t)arow * 256 + acol;
#pragma unroll
      for (int kc = 0; kc < 8; kc++) A[kc] = ld_packed(src + kc * 32);
      f32x4 acc[4] = {zz, zz, zz, zz};
#pragma unroll
      for (int kc = 0; kc < 8; kc++)
#pragma unroll
        for (int j = 0; j < 4; j++) {
          acc[j] = mfma_(A[kc].h, Wq[j][kc], acc[j]);
          acc[j] = mfma_(A[kc].m, Wq[j][kc], acc[j]);
        }
      float* qd = (float*)(qap + (size_t)(t & 3) * 8192);
#pragma unroll
      for (int j = 0; j < 2; j++)
#pragma unroll
        for (int e = 0; e < 4; e++) {
          int row = q * 4 + e, col = c0 + 16 * j + (lane & 15);
          qd[row * 512 + col] = acc[j][e];
          qd[row * 512 + 256 + col] = acc[2 + j][e];
        }
      asm volatile("s_waitcnt vmcnt(0)" ::: "memory");
      if (!fast) __threadfence();
      if (lane == 0) stflag(myslot, t + 1);
      ready = fast ? lcheck(qpn, (lane == 0) ? t + 2 : t - 2, qact) : 0;
    }
  } else if (role == 3) {
    //=========== Qb: L1 n1 partials from h0[t] -- pipelined ===========================
    short8 Wq[2][8];  // 16 short8 = 64 VGPR
#pragma unroll
    for (int kc = 0; kc < 8; kc++)
#pragma unroll
      for (int j = 0; j < 2; j++) Wq[j][kc] = ldw1(Wn1, H_, c0 + 16 * j, kc, lane);
    const int qact = lane < 2;
    const int* qpn = fg + ((lane == 0) ? 8 : 9);
    int* myslot = fg + 18 + wv;
    for (int t = 0; t < T_; t++) {
      if (!ready) aborted = lpoll(qpn, (lane == 0) ? t + 1 : t - 3, qact, aborted);
      if (!fast) __threadfence();
      CFENCE();
      frag2 A[8];
      const uint_t* src = h0r + (size_t)(t & 3) * 4096 + (size_t)arow * 256 + acol;
#pragma unroll
      for (int kc = 0; kc < 8; kc++) A[kc] = ld_packed(src + kc * 32);
      f32x4 acc[2] = {zz, zz};
#pragma unroll
      for (int kc = 0; kc < 8; kc++)
#pragma unroll
        for (int j = 0; j < 2; j++) {
          acc[j] = mfma_(A[kc].h, Wq[j][kc], acc[j]);
          acc[j] = mfma_(A[kc].m, Wq[j][kc], acc[j]);
        }
      float* qd = (float*)(qbp + (size_t)(t & 3) * 4096);
#pragma unroll
      for (int j = 0; j < 2; j++)
#pragma unroll
        for (int e = 0; e < 4; e++) {
          int row = q * 4 + e, col = c0 + 16 * j + (lane & 15);
          qd[row * 256 + col] = acc[j][e];
        }
      asm volatile("s_waitcnt vmcnt(0)" ::: "memory");
      if (!fast) __threadfence();
      if (lane == 0) stflag(myslot, t + 1);
      ready = fast ? lcheck(qpn, (lane == 0) ? t + 2 : t - 2, qact) : 0;
    }
  } else {
    //=========== R: h1 recurrence, INTRA-CU; consumes pipelined Q partials ============
    short8 Wvr[2][8], Wvz[2][8];  // 128 VGPR
#pragma unroll
    for (int j = 0; j < 2; j++)
#pragma unroll
      for (int kc = 0; kc < 8; kc++) {
        Wvr[j][kc] = ldw1(Wh1, H_, c0 + 16 * j, kc, lane);
        Wvz[j][kc] = ldw1(Wh1, H_, 256 + c0 + 16 * j, kc, lane);
      }
    // lanes 0-7: sQa[l] >= t+1 ; 8-15: sQb[l-8] >= t+1
    const int ract = lane < 16;
    const int* rpn = fg + ((lane < 8) ? 10 + lane : 18 + (lane - 8));
    float hnv[2][4];
    for (int t = 0; t < T_; t++) {
      if (!ready) aborted = lpoll(rpn, t + 1, ract, aborted);
      if (!fast) __threadfence();
      CFENCE();
      const uint_t* qas = qap + (size_t)(t & 3) * 8192;
      const uint_t* qbs = qbp + (size_t)(t & 3) * 4096;
      float qr[2][4], qz[2][4], qn[2][4];
#pragma unroll
      for (int j = 0; j < 2; j++)
#pragma unroll
        for (int e = 0; e < 4; e++) {
          int row = q * 4 + e, col = c0 + 16 * j + (lane & 15);
          qr[j][e] = ldf32(qas + row * 512 + col);
          qz[j][e] = ldf32(qas + row * 512 + 256 + col);
          qn[j][e] = ldf32(qbs + row * 256 + col);
        }
      const int par = (t + 1) & 1;
      f32x4 accr[2] = {zz, zz}, accz[2] = {zz, zz};
#pragma unroll
      for (int kc = 0; kc < 8; kc++) {
        short8 ah = *(const short8*)&hp[par][0][arow][kc * 32 + acol];
        short8 am = *(const short8*)&hp[par][1][arow][kc * 32 + acol];
#pragma unroll
        for (int j = 0; j < 2; j++) {
          accr[j] = mfma_(ah, Wvr[j][kc], accr[j]); accr[j] = mfma_(am, Wvr[j][kc], accr[j]);
          accz[j] = mfma_(ah, Wvz[j][kc], accz[j]); accz[j] = mfma_(am, Wvz[j][kc], accz[j]);
        }
      }
#pragma unroll
      for (int j = 0; j < 2; j++)
#pragma unroll
        for (int e = 0; e < 4; e++) {
          int row = q * 4 + e, col = c0 + 16 * j + (lane & 15);
          float gr = accr[j][e] + qr[j][e];
          float gz = accz[j][e] + qz[j][e];
          float h = hf[row][col];
          float hn = cellpw_fast(gr, gz, qn[j][e], h);
          hf[row][col] = hn;
          ushort_t hi = f2bf(hn), mid = f2bf(hn - bf2f(hi));
          hp[t & 1][0][row][col] = hi;
          hp[t & 1][1][row][col] = mid;
          hnv[j][e] = hn;
        }
      __syncthreads();  // orders LDS h1[t] for next step
      if (tid == 0) { if (!fast) __threadfence(); stflag(fg + 9, t + 1); }
      // out[t] HBM stores AFTER the bump: drain overlaps next step
#pragma unroll
      for (int j = 0; j < 2; j++)
#pragma unroll
        for (int e = 0; e < 4; e++) {
          int row = q * 4 + e, col = c0 + 16 * j + (lane & 15);
          out[((size_t)t * B_ + gb + row) * H_ + col] = hnv[j][e];
        }
      ready = fast ? lcheck(rpn, t + 2, ract) : 0;
    }
#pragma unroll
    for (int j = 0; j < 2; j++)
#pragma unroll
      for (int e = 0; e < 4; e++) {
        int row = q * 4 + e, col = c0 + 16 * j + (lane & 15);
        out[(size_t)T_ * B_ * H_ + (size_t)B_ * H_ + (size_t)(gb + row) * H_ + col] =
            hf[row][col];
      }
  }

  // diagnostic sentinel: spin abort signature
  if (tid == 0 && aborted) out[(size_t)gb * H_] = 4096.0f;
}

extern "C" void kernel_launch(void* const* d_in, const int* in_sizes, int n_in,
                              void* d_out, int out_size, void* d_ws, size_t ws_size,
                              hipStream_t stream) {
  const float* x     = (const float*)d_in[0];
  const float* state = (const float*)d_in[1];
  const float* Wi0   = (const float*)d_in[2];
  const float* Wh0   = (const float*)d_in[3];
  const float* Wn0   = (const float*)d_in[4];
  const float* Wi1   = (const float*)d_in[5];
  const float* Wh1   = (const float*)d_in[6];
  const float* Wn1   = (const float*)d_in[7];
  float* out = (float*)d_out;
  uint_t* ws = (uint_t*)d_ws;

  prep_kernel<<<dim3((N_FLAGS + 255) / 256), dim3(256), 0, stream>>>(ws);

  gru_main<<<dim3(80), dim3(512), 0, stream>>>(
      x, Wi0, Wh0, Wn0, Wi1, Wh1, Wn1, state, out, ws, nullptr);
}